// Round 4
// baseline (165.858 us; speedup 1.0000x reference)
//
#include <hip/hip_runtime.h>
#include <math.h>

#define MAX_SPIKE_TIME 100000.0f
#define EPSILON 1e-10f
#define K_IN 1025       // IN_SIZE + bias
#define M_OUT 1024
#define BATCH 64

#define K_MAIN 1024     // ping-pong main loop covers k = 0..1023; k=1024 in epilogue
#define UNROLL 16

// ---------------------------------------------------------------------------
// Kernel 1: stable rank via scalar-pipe stream compares.
// The j-stream X[b][j] is wave-uniform -> compiler emits s_load (scalar cache,
// no LDS, no VMEM per-lane traffic). Branchless bitwise compare; stable
// tie-break (j < i) matches argsort. Bias (j = 1024, t = 1.0) folded in
// analytically. Writes sidx as BYTE offset into W's row block (idx*M*4).
// ---------------------------------------------------------------------------
__global__ __launch_bounds__(256) void rank_kernel(const float* __restrict__ X,
                                                   float* __restrict__ sx,
                                                   int* __restrict__ sidx) {
    const int b = blockIdx.y;
    const int i = blockIdx.x * blockDim.x + threadIdx.x;
    if (i >= K_IN) return;
    const float xi = (i < K_IN - 1) ? X[b * (K_IN - 1) + i] : 1.0f;
    const float* __restrict__ Xb = X + b * (K_IN - 1);

    int rank = 0;
#pragma unroll 8
    for (int j = 0; j < K_IN - 1; ++j) {
        const float xj = Xb[j];                       // wave-uniform -> s_load
        rank += (int)((xj < xi) | ((xj == xi) & (j < i)));
    }
    // bias element j = 1024, xj = 1.0: (1<xi) | ((1==xi) & (1024<i)); i<=1024
    rank += (int)(1.0f < xi);

    sx[b * K_IN + rank]   = xi;
    sidx[b * K_IN + rank] = i * (M_OUT * 4);          // byte offset
}

// ---------------------------------------------------------------------------
// Kernel 2: per (b, m) sequential scan, copy-free ping-pong register pipeline.
// Round-3 post-mortem: the wnxt->wcur copy let the allocator collapse the
// prefetch to depth ~2 (VGPR_Count=32!). Here two 16-wide register buffers
// alternate with NO copies: consume A -> refill A (k0+32) -> consume B ->
// refill B (k0+48). Every load batch has a full other-chunk consumption
// (~500 cyc) between issue and use. launch_bounds(256,1): grid is 1 wave/SIMD
// anyway, lift the VGPR cap.
// Division-free validity/min (cand only ever compared; one IEEE div at end).
// cw/cwt cumsums bit-identical to numpy (__fadd_rn/__fmul_rn, no FMA).
// ---------------------------------------------------------------------------
#define SNN_STEP(kk, wval)                                                     \
    {                                                                          \
        const float x  = xs_s[(kk)];                                           \
        const float xn = xs_s[(kk) + 1];                                       \
        const float w  = (wval);                                               \
        cw  = __fadd_rn(cw, w);                                                \
        cwt = __fadd_rn(cwt, __fmul_rn(w, x));                                 \
        const float denom = fmaxf(__fadd_rn(cw, -1.0f), EPSILON);              \
        const bool valid = (cw >= 1.0f)                                        \
                         & (cwt >= __fmul_rn(x, denom))                        \
                         & (cwt <= __fmul_rn(xn, denom));                      \
        const bool better = valid                                              \
                          & (__fmul_rn(cwt, bd) < __fmul_rn(bn, denom));       \
        bn = better ? cwt   : bn;                                              \
        bd = better ? denom : bd;                                              \
    }

__global__ __launch_bounds__(256, 1) void snn_kernel(const float* __restrict__ W,
                                                     const float* __restrict__ sx,
                                                     const int* __restrict__ sidx,
                                                     float* __restrict__ out) {
    const int b = blockIdx.y;
    const int m = blockIdx.x * blockDim.x + threadIdx.x;

    __shared__ float xs_s[K_MAIN + 2 * UNROLL + 2];   // pads = MAX_SPIKE_TIME
    __shared__ int   off_s[K_MAIN + 2 * UNROLL];      // byte offsets; pads = 0

    const float* sxb = sx + b * K_IN;
    const int*   sib = sidx + b * K_IN;
    for (int k = threadIdx.x; k < K_MAIN + 2 * UNROLL; k += 256) {
        if (k < K_IN) { xs_s[k] = sxb[k]; off_s[k] = sib[k]; }
        else          { xs_s[k] = MAX_SPIKE_TIME; off_s[k] = 0; }
    }
    if (threadIdx.x == 0) {
        xs_s[K_MAIN + 2 * UNROLL]     = MAX_SPIKE_TIME;
        xs_s[K_MAIN + 2 * UNROLL + 1] = MAX_SPIKE_TIME;
    }
    __syncthreads();

    const char* Wm = (const char*)(W + m);
#define WLOAD(kk) (*(const float*)(Wm + off_s[(kk)]))

    float cw = 0.0f, cwt = 0.0f;
    float bn = MAX_SPIKE_TIME, bd = 1.0f;   // best candidate as fraction bn/bd

    float wA[UNROLL], wB[UNROLL];
#pragma unroll
    for (int u = 0; u < UNROLL; ++u) wA[u] = WLOAD(u);
#pragma unroll
    for (int u = 0; u < UNROLL; ++u) wB[u] = WLOAD(UNROLL + u);

    for (int k0 = 0; k0 < K_MAIN; k0 += 2 * UNROLL) {
#pragma unroll
        for (int u = 0; u < UNROLL; ++u) SNN_STEP(k0 + u, wA[u]);
#pragma unroll
        for (int u = 0; u < UNROLL; ++u) wA[u] = WLOAD(k0 + 2 * UNROLL + u);
#pragma unroll
        for (int u = 0; u < UNROLL; ++u) SNN_STEP(k0 + UNROLL + u, wB[u]);
#pragma unroll
        for (int u = 0; u < UNROLL; ++u) wB[u] = WLOAD(k0 + 3 * UNROLL + u);
    }

    // epilogue: k = 1024 (wA[0] was refilled from the real off_s[1024])
    SNN_STEP(K_MAIN, wA[0]);

    out[b * M_OUT + m] = bn / bd;   // single IEEE div == ref's fl(cwt/denom)
#undef WLOAD
}

extern "C" void kernel_launch(void* const* d_in, const int* in_sizes, int n_in,
                              void* d_out, int out_size, void* d_ws, size_t ws_size,
                              hipStream_t stream) {
    const float* X = (const float*)d_in[0];   // [64, 1024]
    const float* W = (const float*)d_in[1];   // [1025, 1024]
    float* out = (float*)d_out;               // [64, 1024]

    float* sx   = (float*)d_ws;                                       // [64, 1025]
    int*   sidx = (int*)((char*)d_ws + BATCH * K_IN * sizeof(float)); // [64, 1025]

    dim3 g1((K_IN + 255) / 256, BATCH);
    rank_kernel<<<g1, 256, 0, stream>>>(X, sx, sidx);

    dim3 g2(M_OUT / 256, BATCH);
    snn_kernel<<<g2, 256, 0, stream>>>(W, sx, sidx, out);
}

// Round 5
// 165.733 us; speedup vs baseline: 1.0008x; 1.0008x over previous
//
#include <hip/hip_runtime.h>
#include <math.h>
#include <stdint.h>

#define MAX_SPIKE_TIME 100000.0f
#define EPSILON 1e-10f
#define K_IN 1025       // IN_SIZE + bias
#define M_OUT 1024
#define BATCH 64
#define CH 16           // pipeline chunk (rows per register buffer)
#define NPAD 1056       // off_s length incl. refill overrun pads (992+64)

// Scheduling wall: forbids the compiler from sinking refill loads into the
// consume sections (R3/R4 post-mortem: scheduler collapsed every register
// pipeline to depth ~2, VGPR_Count stuck at 32, one exposed L2 latency/iter).
__device__ __forceinline__ void sched_wall() { __builtin_amdgcn_sched_barrier(0); }

// One scan step. Division-free: cand = cwt/denom is only ever compared, so
// validity/min use cross-multiplication; one IEEE div at the end reproduces
// the ref's fl(cwt/denom). cw/cwt cumsums are bit-identical to numpy
// (__fadd_rn/__fmul_rn, no FMA contraction).
#define SNN_STEP(kk, wval)                                                     \
    {                                                                          \
        const float x  = xs_s[(kk)];                                           \
        const float xn = xs_s[(kk) + 1];                                       \
        const float w  = (wval);                                               \
        cw  = __fadd_rn(cw, w);                                                \
        cwt = __fadd_rn(cwt, __fmul_rn(w, x));                                 \
        const float denom = fmaxf(__fadd_rn(cw, -1.0f), EPSILON);              \
        const bool valid = (cw >= 1.0f)                                        \
                         & (cwt >= __fmul_rn(x, denom))                        \
                         & (cwt <= __fmul_rn(xn, denom));                      \
        const bool better = valid                                              \
                          & (__fmul_rn(cwt, bd) < __fmul_rn(bn, denom));       \
        bn = better ? cwt   : bn;                                              \
        bd = better ? denom : bd;                                              \
    }

__global__ __launch_bounds__(256, 1) void snn_fused(const float* __restrict__ X,
                                                    const float* __restrict__ W,
                                                    float* __restrict__ out) {
    const int b   = blockIdx.y;
    const int tid = threadIdx.x;
    const int m   = blockIdx.x * 256 + tid;

    __shared__ __align__(16) unsigned long long keys[1028];
    __shared__ float xs_s[1027];
    __shared__ int   off_s[NPAD];
    __shared__ int   s_cnt1;

    if (tid == 0) s_cnt1 = 0;
    __syncthreads();

    // ---- phase 0: build stable-sort keys in LDS ------------------------------
    // key = (float_bits(x) << 11) | index : positive floats order as their bit
    // patterns; low bits give the stable (j < i) tie-break exactly.
    const float* Xb = X + b * (K_IN - 1);
    int local1 = 0;
    for (int i = tid; i < K_IN - 1; i += 256) {
        const float v = Xb[i];
        local1 += (int)(v == 1.0f);
        keys[i] = ((unsigned long long)__float_as_uint(v) << 11) | (unsigned)i;
    }
    if (local1) atomicAdd(&s_cnt1, local1);
    if (tid == 0) {
        keys[1024] = ((unsigned long long)__float_as_uint(1.0f) << 11) | 1024u;
        keys[1025] = ~0ull; keys[1026] = ~0ull; keys[1027] = ~0ull;  // rank-neutral
        xs_s[1025] = MAX_SPIKE_TIME;   // next_x sentinel for k = 1024
        xs_s[1026] = MAX_SPIKE_TIME;
    }
    for (int k = 1025 + tid; k < NPAD; k += 256) off_s[k] = 0;  // benign pads
    __syncthreads();

    // ---- phase 1: all-pairs rank (4 keys/thread; bias rank = #(X == 1.0)) ---
    const unsigned long long q0 = keys[tid];
    const unsigned long long q1 = keys[tid + 256];
    const unsigned long long q2 = keys[tid + 512];
    const unsigned long long q3 = keys[tid + 768];
    int r0 = 0, r1 = 0, r2 = 0, r3 = 0;
#pragma unroll 4
    for (int j = 0; j < 1028; j += 2) {
        const ulonglong2 kk = *(const ulonglong2*)&keys[j];   // ds_read_b128
        r0 += (int)(kk.x < q0); r0 += (int)(kk.y < q0);
        r1 += (int)(kk.x < q1); r1 += (int)(kk.y < q1);
        r2 += (int)(kk.x < q2); r2 += (int)(kk.y < q2);
        r3 += (int)(kk.x < q3); r3 += (int)(kk.y < q3);
    }
    xs_s[r0] = __uint_as_float((unsigned)(q0 >> 11)); off_s[r0] = (int)(q0 & 2047u) * 4096;
    xs_s[r1] = __uint_as_float((unsigned)(q1 >> 11)); off_s[r1] = (int)(q1 & 2047u) * 4096;
    xs_s[r2] = __uint_as_float((unsigned)(q2 >> 11)); off_s[r2] = (int)(q2 & 2047u) * 4096;
    xs_s[r3] = __uint_as_float((unsigned)(q3 >> 11)); off_s[r3] = (int)(q3 & 2047u) * 4096;
    if (tid == 0) {
        const int rb = s_cnt1;            // bias key beats exactly the X == 1.0 keys
        xs_s[rb]  = 1.0f;
        off_s[rb] = 1024 * 4096;
    }
    __syncthreads();

    // ---- phase 2: pipelined sequential scan ----------------------------------
    const char* Wm = (const char*)(W + m);
#define WLOAD(kk) (*(const float*)(Wm + off_s[(kk)]))

    float cw = 0.0f, cwt = 0.0f;
    float bn = MAX_SPIKE_TIME, bd = 1.0f;

    float wA[CH], wB[CH];
#pragma unroll
    for (int u = 0; u < CH; ++u) wA[u] = WLOAD(u);
#pragma unroll
    for (int u = 0; u < CH; ++u) wB[u] = WLOAD(CH + u);
    sched_wall();

    for (int c = 0; c < 1024; c += 2 * CH) {
#pragma unroll
        for (int u = 0; u < CH; ++u) SNN_STEP(c + u, wA[u]);
        sched_wall();
#pragma unroll
        for (int u = 0; u < CH; ++u) wA[u] = WLOAD(c + 2 * CH + u);  // rows ≤ 1039 (padded)
        sched_wall();
#pragma unroll
        for (int u = 0; u < CH; ++u) SNN_STEP(c + CH + u, wB[u]);
        sched_wall();
#pragma unroll
        for (int u = 0; u < CH; ++u) wB[u] = WLOAD(c + 3 * CH + u);  // rows ≤ 1055 (padded)
        sched_wall();
    }

    // epilogue: k = 1024 (wA[0] refilled from the real off_s[1024] at c = 992)
    SNN_STEP(1024, wA[0]);

    out[b * M_OUT + m] = bn / bd;   // single IEEE div == ref's fl(cwt/denom)
#undef WLOAD
}

extern "C" void kernel_launch(void* const* d_in, const int* in_sizes, int n_in,
                              void* d_out, int out_size, void* d_ws, size_t ws_size,
                              hipStream_t stream) {
    const float* X = (const float*)d_in[0];   // [64, 1024]
    const float* W = (const float*)d_in[1];   // [1025, 1024]
    float* out = (float*)d_out;               // [64, 1024]

    dim3 grid(M_OUT / 256, BATCH);
    snn_fused<<<grid, 256, 0, stream>>>(X, W, out);
}

// Round 7
// 134.911 us; speedup vs baseline: 1.2294x; 1.2285x over previous
//
#include <hip/hip_runtime.h>
#include <math.h>

#define MAXT 100000.0f
#define EPSILON 1e-10f
#define K_IN 1025       // IN_SIZE + bias
#define M_OUT 1024
#define BATCH 64
#define PITCH 1056      // padded row pitch: refill overruns to index 1055 (s=3)
#define CH 16           // pipeline chunk

// ---------------------------------------------------------------------------
// Kernel 1: stable rank via branchless u64 keys in LDS (all-pairs), plus:
//  - initializes out[] to MAXT (scan kernel atomicMins into it afterwards)
//  - writes sentinel pads sx[1025..1055]=MAXT, soff[...]=0 (safe dummy loads)
//    (ws is re-poisoned 0xAA before every launch -> MUST rewrite all pads;
//     R6 crashed on exactly this: off[1041..1055] read 0xAAAAAAAA -> 2.8 GB
//     byte offset into W -> illegal address)
// key = (float_bits(x) << 11) | index : positive floats order as bit patterns;
// low bits give the stable (j < i) argsort tie-break exactly.
// ---------------------------------------------------------------------------
__global__ __launch_bounds__(256) void rank_kernel(const float* __restrict__ X,
                                                   float* __restrict__ sx,
                                                   int* __restrict__ soff,
                                                   float* __restrict__ out) {
    const int b = blockIdx.y;
    const int tid = threadIdx.x;
    __shared__ __align__(16) unsigned long long keys[1028];
    for (int i = tid; i < 1028; i += 256) {
        float v;
        if (i < 1024)       v = X[b * 1024 + i];
        else if (i == 1024) v = 1.0f;                     // bias spike time
        else                v = __builtin_huge_valf();    // rank-neutral pad
        keys[i] = ((unsigned long long)__float_as_uint(v) << 11) | (unsigned)i;
    }
    if (blockIdx.x < 4) out[b * M_OUT + blockIdx.x * 256 + tid] = MAXT;  // init for atomicMin
    __syncthreads();

    const int i = blockIdx.x * 256 + tid;
    if (i > 1024) {
        if (i < PITCH) { sx[b * PITCH + i] = MAXT; soff[b * PITCH + i] = 0; }  // sentinels
        return;
    }
    const unsigned long long ki = keys[i];
    int rank = 0;
#pragma unroll 8
    for (int j = 0; j < 1028; j += 2) {
        const ulonglong2 kk = *(const ulonglong2*)&keys[j];   // ds_read_b128, uniform j
        rank += (int)(kk.x < ki);
        rank += (int)(kk.y < ki);
    }
    sx[b * PITCH + rank]   = __uint_as_float((unsigned)(ki >> 11));
    soff[b * PITCH + rank] = (int)(ki & 2047u) * 4096;        // byte offset into W
}

// ---------------------------------------------------------------------------
// Kernel 2: K-split scan. grid (4 mblocks, 64 b, 4 segments). Wave for
// segment s replays the exact sequential cumsum for k < s*256 (2 VALU + 1
// load per step, bit-identical __fadd_rn order), then full validity work in
// [s*256, s*256+256) (+ k=1024 epilogue for s=3). 4096 waves -> 4/SIMD TLP.
// off/xs are read with wave-uniform indices from __restrict__ const global
// -> scalarized to s_load (no LDS, no per-load VGPR addressing: R4/R5's
// serialized ds_read->global_load chain is gone).
// Division-free validity/min (cross-multiply); one IEEE div per segment;
// atomicMin on float bits (all candidates >= 1 > 0, uint-min == float-min).
// ---------------------------------------------------------------------------
#define SNN_STEP(kk, wval)                                                     \
    {                                                                          \
        const float x  = xs[(kk)];                                             \
        const float xn = xs[(kk) + 1];                                         \
        const float w  = (wval);                                               \
        cw  = __fadd_rn(cw, w);                                                \
        cwt = __fadd_rn(cwt, __fmul_rn(w, x));                                 \
        const float denom = fmaxf(__fadd_rn(cw, -1.0f), EPSILON);              \
        const bool valid = (cw >= 1.0f)                                        \
                         & (cwt >= __fmul_rn(x, denom))                        \
                         & (cwt <= __fmul_rn(xn, denom));                      \
        const bool better = valid                                              \
                          & (__fmul_rn(cwt, bd) < __fmul_rn(bn, denom));       \
        bn = better ? cwt   : bn;                                              \
        bd = better ? denom : bd;                                              \
    }

#define PFX_STEP(kk, wval)                                                     \
    {                                                                          \
        const float w = (wval);                                                \
        cw  = __fadd_rn(cw, w);                                                \
        cwt = __fadd_rn(cwt, __fmul_rn(w, xs[(kk)]));                          \
    }

__global__ __launch_bounds__(256, 1) void snn_scan(const float* __restrict__ W,
                                                   const float* __restrict__ sx,
                                                   const int* __restrict__ soff,
                                                   float* __restrict__ out) {
    const int b = blockIdx.y;
    const int s = blockIdx.z;
    const int m = blockIdx.x * 256 + threadIdx.x;

    const float* __restrict__ xs  = sx   + b * PITCH;
    const int*   __restrict__ off = soff + b * PITCH;
    const char* Wm = (const char*)(W + m);
#define WLOAD(kk) (*(const float*)(Wm + off[(kk)]))

    const int kseg = s * 256;
    float cw = 0.0f, cwt = 0.0f;

    float wA[CH], wB[CH];
#pragma unroll
    for (int u = 0; u < CH; ++u) wA[u] = WLOAD(u);
#pragma unroll
    for (int u = 0; u < CH; ++u) wB[u] = WLOAD(CH + u);
    __builtin_amdgcn_sched_barrier(0);

    // ---- exact prefix replay: k in [0, kseg), cheap steps ----
    for (int k0 = 0; k0 < kseg; k0 += 2 * CH) {
#pragma unroll
        for (int u = 0; u < CH; ++u) PFX_STEP(k0 + u, wA[u]);
        __builtin_amdgcn_sched_barrier(0);
#pragma unroll
        for (int u = 0; u < CH; ++u) wA[u] = WLOAD(k0 + 2 * CH + u);
        __builtin_amdgcn_sched_barrier(0);
#pragma unroll
        for (int u = 0; u < CH; ++u) PFX_STEP(k0 + CH + u, wB[u]);
        __builtin_amdgcn_sched_barrier(0);
#pragma unroll
        for (int u = 0; u < CH; ++u) wB[u] = WLOAD(k0 + 3 * CH + u);
        __builtin_amdgcn_sched_barrier(0);
    }
    // invariant here: wA = W rows [kseg..kseg+15], wB = [kseg+16..kseg+31]

    // ---- owned segment: k in [kseg, kseg+256), full validity ----
    float bn = MAXT, bd = 1.0f;
    for (int k0 = kseg; k0 < kseg + 256; k0 += 2 * CH) {
#pragma unroll
        for (int u = 0; u < CH; ++u) SNN_STEP(k0 + u, wA[u]);
        __builtin_amdgcn_sched_barrier(0);
#pragma unroll
        for (int u = 0; u < CH; ++u) wA[u] = WLOAD(k0 + 2 * CH + u);   // max idx kseg+271 <= 1039
        __builtin_amdgcn_sched_barrier(0);
#pragma unroll
        for (int u = 0; u < CH; ++u) SNN_STEP(k0 + CH + u, wB[u]);
        __builtin_amdgcn_sched_barrier(0);
#pragma unroll
        for (int u = 0; u < CH; ++u) wB[u] = WLOAD(k0 + 3 * CH + u);   // max idx kseg+287 <= 1055
        __builtin_amdgcn_sched_barrier(0);
    }
    if (s == 3) SNN_STEP(1024, wA[0]);   // epilogue: wA[0] refilled from off[1024]

    const float cand = bn / bd;          // single IEEE div == ref's fl(cwt/denom)
    atomicMin((unsigned int*)(out + b * M_OUT + m), __float_as_uint(cand));
#undef WLOAD
}

extern "C" void kernel_launch(void* const* d_in, const int* in_sizes, int n_in,
                              void* d_out, int out_size, void* d_ws, size_t ws_size,
                              hipStream_t stream) {
    const float* X = (const float*)d_in[0];   // [64, 1024]
    const float* W = (const float*)d_in[1];   // [1025, 1024]
    float* out = (float*)d_out;               // [64, 1024]

    float* sx   = (float*)d_ws;                                        // [64, PITCH]
    int*   soff = (int*)((char*)d_ws + BATCH * PITCH * sizeof(float)); // [64, PITCH]

    dim3 g1(5, BATCH);
    rank_kernel<<<g1, 256, 0, stream>>>(X, sx, soff, out);

    dim3 g2(M_OUT / 256, BATCH, 4);
    snn_scan<<<g2, 256, 0, stream>>>(W, sx, soff, out);
}